// Round 6
// baseline (307.527 us; speedup 1.0000x reference)
//
#include <hip/hip_runtime.h>
#include <hip/hip_bf16.h>

typedef unsigned short u16;
typedef unsigned int u32;

#define N_Q 4096
#define N_M 100000
#define N_M_PAD 100096      // 1564 * 64
#define DDIM 128
#define QTILE 128
#define MTILE 64
#define NCHUNK 16
#define NQT (N_Q / QTILE)                      // 32
#define TOTAL_MT (N_M_PAD / MTILE)             // 1564
#define TPC ((TOTAL_MT + NCHUNK - 1) / NCHUNK) // 98
#define NCAND (NCHUNK * 2 * 3)                 // 96 candidates/query

typedef short bf16x8 __attribute__((ext_vector_type(8)));
typedef float f32x4 __attribute__((ext_vector_type(4)));

static __device__ __forceinline__ u16 f2bf(float v) {
  union { float f; u32 u; } a; a.f = v;
  u32 r = a.u + 0x7fffu + ((a.u >> 16) & 1u);
  return (u16)(r >> 16);
}

// ---------------- kernel 1: L2 norms + bf16 normalized copies (grid-stride) ----------------
__global__ __launch_bounds__(256) void knorm(const float* __restrict__ q, const float* __restrict__ m,
                                             u16* __restrict__ qn, u16* __restrict__ mn,
                                             float* __restrict__ qinv, float* __restrict__ minv) {
  const int lane = threadIdx.x & 63;
  const int nw = gridDim.x * 4;
  for (int row = blockIdx.x * 4 + (threadIdx.x >> 6); row < N_Q + N_M_PAD; row += nw) {
    const float* src;
    u16* dst;
    int mr = 0;
    bool is_q = (row < N_Q);
    bool pad = false;
    if (is_q) {
      src = q + (size_t)row * DDIM;
      dst = qn + (size_t)row * DDIM;
    } else {
      mr = row - N_Q;
      pad = (mr >= N_M);
      src = m + (size_t)mr * DDIM;
      dst = mn + (size_t)mr * DDIM;
    }
    float2 x;
    if (pad) { x.x = 0.f; x.y = 0.f; }
    else x = ((const float2*)src)[lane];
    float s = x.x * x.x + x.y * x.y;
    #pragma unroll
    for (int off = 1; off < 64; off <<= 1) s += __shfl_xor(s, off, 64);
    float invn = 1.0f / fmaxf(sqrtf(s), 1e-12f);
    u32 packed = (u32)f2bf(x.x * invn) | ((u32)f2bf(x.y * invn) << 16);
    ((u32*)dst)[lane] = packed;
    if (lane == 0) {
      if (is_q) qinv[row] = invn;
      else minv[mr] = pad ? 0.f : invn;
    }
  }
}

// ---------------- kernel 2 helpers ----------------
static __device__ __forceinline__ void loadF(bf16x8 (&F)[8], const u16* pt, const u32* voff) {
  #pragma unroll
  for (int i = 0; i < 8; ++i)
    F[i] = *(const bf16x8*)(pt + voff[i]);
}

// one 64-row tile: 32 MFMA + batch-max screening epilogue (packed code in mantissa)
static __device__ __forceinline__ void tileWork(
    const bf16x8 (&F)[8], int tl, int quad,
    const bf16x8 (&bq)[4][4], float (&tv0)[4], float (&tv1)[4], float (&tv2)[4]) {
  f32x4 acc[2][4];  // [mi][ni]
  {
    f32x4 z = {0.f, 0.f, 0.f, 0.f};
    #pragma unroll
    for (int ni = 0; ni < 4; ++ni) {
      acc[0][ni] = __builtin_amdgcn_mfma_f32_16x16x32_bf16(F[0], bq[ni][0], z, 0, 0, 0);
      acc[1][ni] = __builtin_amdgcn_mfma_f32_16x16x32_bf16(F[1], bq[ni][0], z, 0, 0, 0);
    }
  }
  #pragma unroll
  for (int s = 1; s < 4; ++s) {
    #pragma unroll
    for (int ni = 0; ni < 4; ++ni) {
      acc[0][ni] = __builtin_amdgcn_mfma_f32_16x16x32_bf16(F[s * 2 + 0], bq[ni][s], acc[0][ni], 0, 0, 0);
      acc[1][ni] = __builtin_amdgcn_mfma_f32_16x16x32_bf16(F[s * 2 + 1], bq[ni][s], acc[1][ni], 0, 0, 0);
    }
  }
  const u32 code = ((u32)tl << 2) | (u32)quad;  // < 392, 9 bits
  #pragma unroll
  for (int ni = 0; ni < 4; ++ni) {
    f32x4 x0 = acc[0][ni], x1 = acc[1][ni];
    float M = fmaxf(fmaxf(fmaxf(x0[0], x0[1]), fmaxf(x0[2], x0[3])),
                    fmaxf(fmaxf(x1[0], x1[1]), fmaxf(x1[2], x1[3])));
    float pk = __uint_as_float((__float_as_uint(M) & 0xFFFFFE00u) | code);
    tv2[ni] = __builtin_amdgcn_fmed3f(tv1[ni], tv2[ni], pk);
    tv1[ni] = __builtin_amdgcn_fmed3f(tv0[ni], tv1[ni], pk);
    tv0[ni] = fmaxf(tv0[ni], pk);
  }
}

// ---------------- kernel 2: LDS-free, barrier-free MFMA GEMM + batch-max screening ----------------
// grid 512 = 32 qtiles x 16 chunks (2 blocks/CU, 8 waves/CU). A-tiles stream global->VGPR,
// double-buffered in two register sets; per-wave pipeline, no __syncthreads.
__global__ __launch_bounds__(256, 2) void kgemm(const u16* __restrict__ qn,
                                                const u16* __restrict__ mn,
                                                float* __restrict__ pval) {
  const int id = blockIdx.x;                  // 0..511
  const int xcd = id & 7, sub = id >> 3;      // XCD-aware: 2 chunks per XCD (3.2 MB in L2)
  const int ch = xcd * 2 + (sub >> 5);        // 0..15
  const int qt = sub & 31;                    // 0..31
  const int tid = threadIdx.x;
  const int wid = tid >> 6, lane = tid & 63;
  const int quad = lane >> 4, l15 = lane & 15;
  const int wm = wid >> 1, wq = wid & 1;

  const int t0 = ch * TPC;
  const int t1 = (t0 + TPC < TOTAL_MT) ? (t0 + TPC) : TOTAL_MT;
  const int nt = t1 - t0;

  // per-lane element offsets for the 8 A-fragments [s][mi] within a 64x128 tile
  u32 voff[8];
  #pragma unroll
  for (int s = 0; s < 4; ++s)
    #pragma unroll
    for (int mi = 0; mi < 2; ++mi)
      voff[s * 2 + mi] = (u32)((wm * 32 + mi * 16 + l15) * DDIM + (s * 4 + quad) * 8);

  // B (query) fragments: loop-invariant, in registers (64 VGPRs)
  bf16x8 bq[4][4];  // [ni][s]
  #pragma unroll
  for (int ni = 0; ni < 4; ++ni) {
    int col = qt * QTILE + wq * 64 + ni * 16 + l15;
    #pragma unroll
    for (int s = 0; s < 4; ++s)
      bq[ni][s] = *(const bf16x8*)&qn[(size_t)col * DDIM + (s * 4 + quad) * 8];
  }

  float tv0[4], tv1[4], tv2[4];
  #pragma unroll
  for (int i = 0; i < 4; ++i) { tv0[i] = tv1[i] = tv2[i] = -1e30f; }

  bf16x8 F0[8], F1[8];
  loadF(F0, mn + (size_t)t0 * (MTILE * DDIM), voff);

  int tl = 0;
  while (true) {
    if (tl + 1 < nt) loadF(F1, mn + (size_t)(t0 + tl + 1) * (MTILE * DDIM), voff);
    tileWork(F0, tl, quad, bq, tv0, tv1, tv2);
    ++tl; if (tl >= nt) break;
    if (tl + 1 < nt) loadF(F0, mn + (size_t)(t0 + tl + 1) * (MTILE * DDIM), voff);
    tileWork(F1, tl, quad, bq, tv0, tv1, tv2);
    ++tl; if (tl >= nt) break;
  }

  // cross-quad merge of sorted-3 lists, then coalesced write (3 survivors per wm)
  #pragma unroll
  for (int ni = 0; ni < 4; ++ni) {
    float a0 = tv0[ni], a1 = tv1[ni], a2 = tv2[ni];
    #pragma unroll
    for (int off = 16; off <= 32; off <<= 1) {
      float b0 = __shfl_xor(a0, off, 64);
      float b1 = __shfl_xor(a1, off, 64);
      float b2 = __shfl_xor(a2, off, 64);
      float n0 = fmaxf(a0, b0);
      float n1 = __builtin_amdgcn_fmed3f(a0, b0, fmaxf(a1, b1));
      float n2 = fmaxf(fmaxf(fminf(a1, b0), fminf(a0, b1)), fmaxf(a2, b2));
      a0 = n0; a1 = n1; a2 = n2;
    }
    float v = (quad == 0) ? a0 : ((quad == 1) ? a1 : a2);
    if (quad < 3) {
      int qlocal = wq * 64 + ni * 16 + l15;
      size_t base = (((size_t)qt * NCHUNK + ch) * QTILE + qlocal) * 6 + wm * 3 + quad;
      pval[base] = v;
    }
  }
}

// ---------------- kernel 3: top-8 batches, coalesced fp32 rescore of 64 rows, top-3 ----------------
__global__ __launch_bounds__(256) void kmerge(const float* __restrict__ pval,
                                              const float* __restrict__ q,
                                              const float* __restrict__ mem,
                                              const float* __restrict__ qinv,
                                              const float* __restrict__ minv,
                                              float* __restrict__ out) {
  __shared__ float sv[4][64];
  const int tid = threadIdx.x;
  const int wq = tid >> 6;
  const int lane = tid & 63;
  const int qg = blockIdx.x * 4 + wq;
  const int qt = qg >> 7, ql = qg & 127;

  // load 96 candidates: lanes 0..47 own 2 each
  const int c0 = lane * 2;
  float cv[2] = {-1e31f, -1e31f};
  if (c0 < NCAND) {
    int chn = c0 / 6, rem = c0 - chn * 6;   // c0 even, rem in {0,2,4} -> rem+1 same chunk
    size_t b = (((size_t)qt * NCHUNK + chn) * QTILE + ql) * 6 + rem;
    cv[0] = pval[b];
    cv[1] = pval[b + 1];
  }

  // 8 argmax passes (packed val desc, pos asc tiebreak), shuffle-only
  float wv[8]; int wp[8];
  #pragma unroll
  for (int pass = 0; pass < 8; ++pass) {
    float bv = cv[0]; int bp = c0;
    bool g1 = (cv[1] > bv);
    bv = g1 ? cv[1] : bv; bp = g1 ? (c0 + 1) : bp;
    #pragma unroll
    for (int off = 32; off >= 1; off >>= 1) {
      float ov = __shfl_xor(bv, off, 64);
      int op = __shfl_xor(bp, off, 64);
      bool g = (ov > bv) || (ov == bv && op < bp);
      bv = g ? ov : bv; bp = g ? op : bp;
    }
    wv[pass] = bv; wp[pass] = bp;
    if (c0 == bp) cv[0] = -1e31f;
    if (c0 + 1 == bp) cv[1] = -1e31f;
  }

  const float qi = qinv[qg];
  const float* qrow = q + (size_t)qg * DDIM;
  const int e = lane >> 3, f = lane & 7;

  // rescore top-8 batches, 8 rows each; 8 lanes/row, 128B-coalesced segments
  #pragma unroll
  for (int p = 0; p < 8; ++p) {
    int bp = wp[p];
    u32 code = __float_as_uint(wv[p]) & 511u;
    int chn = bp / 6;
    int wm = (bp - chn * 6) / 3;
    int tl = (int)(code >> 2), qd = (int)(code & 3u);
    int row = (chn * TPC + tl) * MTILE + wm * 32 + (e >> 2) * 16 + qd * 4 + (e & 3);
    bool valid = (row < N_M);
    int ra = valid ? row : 0;
    const float* mrow = mem + (size_t)ra * DDIM;
    float s = 0.f;
    #pragma unroll
    for (int i = 0; i < 4; ++i) {
      float4 mv = *(const float4*)&mrow[(f + 8 * i) * 4];
      float4 qv = *(const float4*)&qrow[(f + 8 * i) * 4];
      s += qv.x * mv.x + qv.y * mv.y + qv.z * mv.z + qv.w * mv.w;
    }
    #pragma unroll
    for (int off = 1; off < 8; off <<= 1) s += __shfl_xor(s, off, 64);  // within octet
    s = valid ? (s * qi * minv[ra]) : -1e30f;
    if (f == 0) sv[wq][p * 8 + e] = s;
  }
  __syncthreads();

  // my (row, val): entry = lane -> pass p = lane>>3, elem e2 = lane&7
  float myv = sv[wq][lane];
  {
    int p = lane >> 3, e2 = lane & 7;
    int bp = wp[p];
    u32 code = __float_as_uint(wv[p]) & 511u;
    int chn = bp / 6;
    int wm = (bp - chn * 6) / 3;
    int tl = (int)(code >> 2), qd = (int)(code & 3u);
    int row = (chn * TPC + tl) * MTILE + wm * 32 + (e2 >> 2) * 16 + qd * 4 + (e2 & 3);
    int myrow = (row < N_M) ? row : (N_M + lane);

    // 3 selection passes over 64 exact values (val desc, row asc)
    #pragma unroll
    for (int a = 0; a < 3; ++a) {
      float bv = myv; int bi = myrow;
      #pragma unroll
      for (int off = 32; off >= 1; off >>= 1) {
        float ov = __shfl_xor(bv, off, 64);
        int oi = __shfl_xor(bi, off, 64);
        bool g2 = (ov > bv) || (ov == bv && oi < bi);
        bv = g2 ? ov : bv; bi = g2 ? oi : bi;
      }
      if (lane == 0) {
        out[(size_t)qg * 3 + a] = 1.0f - bv;
        out[(size_t)N_Q * 3 + (size_t)qg * 3 + a] = (float)bi;
      }
      if (myrow == bi) myv = -1e31f;
    }
  }
}

extern "C" void kernel_launch(void* const* d_in, const int* in_sizes, int n_in,
                              void* d_out, int out_size, void* d_ws, size_t ws_size,
                              hipStream_t stream) {
  const float* q = (const float*)d_in[0];
  const float* m = (const float*)d_in[1];

  char* ws = (char*)d_ws;
  size_t off = 0;
  u16* qn = (u16*)(ws + off); off += (size_t)N_Q * DDIM * 2;        // 1 MB
  u16* mn = (u16*)(ws + off); off += (size_t)N_M_PAD * DDIM * 2;    // 25.6 MB
  float* qinv = (float*)(ws + off); off += (size_t)N_Q * 4;
  float* minv = (float*)(ws + off); off += (size_t)N_M_PAD * 4;
  float* pval = (float*)(ws + off); off += (size_t)N_Q * NCAND * 4; // 1.6 MB

  knorm<<<1024, 256, 0, stream>>>(q, m, qn, mn, qinv, minv);
  kgemm<<<NQT * NCHUNK, 256, 0, stream>>>(qn, mn, pval);
  kmerge<<<N_Q / 4, 256, 0, stream>>>(pval, q, m, qinv, minv, (float*)d_out);
}

// Round 7
// 213.077 us; speedup vs baseline: 1.4433x; 1.4433x over previous
//
#include <hip/hip_runtime.h>
#include <hip/hip_bf16.h>

typedef unsigned short u16;
typedef unsigned int u32;

#define N_Q 4096
#define N_M 100000
#define N_M_PAD 100096      // 1564 * 64
#define DDIM 128
#define QTILE 128
#define MTILE 64
#define NCHUNK 16
#define NQT (N_Q / QTILE)                      // 32
#define TOTAL_MT (N_M_PAD / MTILE)             // 1564
#define TPC ((TOTAL_MT + NCHUNK - 1) / NCHUNK) // 98
#define NCAND (NCHUNK * 2 * 3)                 // 96 candidates/query

typedef short bf16x8 __attribute__((ext_vector_type(8)));
typedef float f32x4 __attribute__((ext_vector_type(4)));

static __device__ __forceinline__ u16 f2bf(float v) {
  union { float f; u32 u; } a; a.f = v;
  u32 r = a.u + 0x7fffu + ((a.u >> 16) & 1u);
  return (u16)(r >> 16);
}

static __device__ __forceinline__ void async_copy16(const u16* gp, u16* lp) {
  __builtin_amdgcn_global_load_lds(
      (const __attribute__((address_space(1))) u32*)gp,
      (__attribute__((address_space(3))) u32*)lp, 16, 0, 0);
}

// ---------------- kernel 1: L2 norms + bf16 normalized copies (grid-stride) ----------------
__global__ __launch_bounds__(256) void knorm(const float* __restrict__ q, const float* __restrict__ m,
                                             u16* __restrict__ qn, u16* __restrict__ mn,
                                             float* __restrict__ qinv, float* __restrict__ minv) {
  const int lane = threadIdx.x & 63;
  const int nw = gridDim.x * 4;
  for (int row = blockIdx.x * 4 + (threadIdx.x >> 6); row < N_Q + N_M_PAD; row += nw) {
    const float* src;
    u16* dst;
    int mr = 0;
    bool is_q = (row < N_Q);
    bool pad = false;
    if (is_q) {
      src = q + (size_t)row * DDIM;
      dst = qn + (size_t)row * DDIM;
    } else {
      mr = row - N_Q;
      pad = (mr >= N_M);
      src = m + (size_t)mr * DDIM;
      dst = mn + (size_t)mr * DDIM;
    }
    float2 x;
    if (pad) { x.x = 0.f; x.y = 0.f; }
    else x = ((const float2*)src)[lane];
    float s = x.x * x.x + x.y * x.y;
    #pragma unroll
    for (int off = 1; off < 64; off <<= 1) s += __shfl_xor(s, off, 64);
    float invn = 1.0f / fmaxf(sqrtf(s), 1e-12f);
    u32 packed = (u32)f2bf(x.x * invn) | ((u32)f2bf(x.y * invn) << 16);
    ((u32*)dst)[lane] = packed;
    if (lane == 0) {
      if (is_q) qinv[row] = invn;
      else minv[mr] = pad ? 0.f : invn;
    }
  }
}

// ---------------- kernel 2 helpers ----------------
static __device__ __forceinline__ void stage4(const u16* __restrict__ mn, u16* dst,
                                              int t, const u32* goff, u32 loff0) {
  const u16* gbase = mn + (size_t)t * MTILE * DDIM;
  #pragma unroll
  for (int it = 0; it < 4; ++it)
    async_copy16(gbase + goff[it], dst + loff0 + (u32)(it * 64) * 8);
}

// one 64-row tile: 32 MFMA + batch-max screening epilogue (packed code in mantissa)
static __device__ __forceinline__ void tileWork(
    const u16* As, int tl, int wm, int quad, int l15,
    const bf16x8 (&bq)[4][4], float (&tv0)[4], float (&tv1)[4], float (&tv2)[4]) {
  f32x4 acc[2][4];  // [mi][ni]
  {
    int c = quad ^ l15;
    bf16x8 a0 = *(const bf16x8*)&As[((wm * 32 + l15) * 16 + c) * 8];
    bf16x8 a1 = *(const bf16x8*)&As[((wm * 32 + 16 + l15) * 16 + c) * 8];
    f32x4 z = {0.f, 0.f, 0.f, 0.f};
    #pragma unroll
    for (int ni = 0; ni < 4; ++ni) {
      acc[0][ni] = __builtin_amdgcn_mfma_f32_16x16x32_bf16(a0, bq[ni][0], z, 0, 0, 0);
      acc[1][ni] = __builtin_amdgcn_mfma_f32_16x16x32_bf16(a1, bq[ni][0], z, 0, 0, 0);
    }
  }
  #pragma unroll
  for (int s = 1; s < 4; ++s) {
    int c = (s * 4 + quad) ^ l15;
    bf16x8 a0 = *(const bf16x8*)&As[((wm * 32 + l15) * 16 + c) * 8];
    bf16x8 a1 = *(const bf16x8*)&As[((wm * 32 + 16 + l15) * 16 + c) * 8];
    #pragma unroll
    for (int ni = 0; ni < 4; ++ni) {
      acc[0][ni] = __builtin_amdgcn_mfma_f32_16x16x32_bf16(a0, bq[ni][s], acc[0][ni], 0, 0, 0);
      acc[1][ni] = __builtin_amdgcn_mfma_f32_16x16x32_bf16(a1, bq[ni][s], acc[1][ni], 0, 0, 0);
    }
  }
  const u32 code = ((u32)tl << 2) | (u32)quad;  // < 392, 9 bits
  #pragma unroll
  for (int ni = 0; ni < 4; ++ni) {
    f32x4 x0 = acc[0][ni], x1 = acc[1][ni];
    float M = fmaxf(fmaxf(fmaxf(x0[0], x0[1]), fmaxf(x0[2], x0[3])),
                    fmaxf(fmaxf(x1[0], x1[1]), fmaxf(x1[2], x1[3])));
    float pk = __uint_as_float((__float_as_uint(M) & 0xFFFFFE00u) | code);
    tv2[ni] = __builtin_amdgcn_fmed3f(tv1[ni], tv2[ni], pk);
    tv1[ni] = __builtin_amdgcn_fmed3f(tv0[ni], tv1[ni], pk);
    tv0[ni] = fmaxf(tv0[ni], pk);
  }
}

// ---------------- kernel 2: 4-deep LDS pipeline, raw s_barrier + manual vmcnt ----------------
// grid 512 = 32 qtiles x 16 chunks (2 blocks/CU). Stage tile t+3 while computing t;
// per round: s_waitcnt vmcnt(8) retires exactly the 3-round-old stage, then bare s_barrier.
// No vmcnt(0) drain ever.
__global__ __launch_bounds__(256, 2) void kgemm(const u16* __restrict__ qn,
                                                const u16* __restrict__ mn,
                                                float* __restrict__ pval) {
  __shared__ u16 B0[MTILE * DDIM];  // 16 KB each
  __shared__ u16 B1[MTILE * DDIM];
  __shared__ u16 B2[MTILE * DDIM];
  __shared__ u16 B3[MTILE * DDIM];

  const int id = blockIdx.x;                  // 0..511
  const int xcd = id & 7, sub = id >> 3;      // XCD-aware: 2 chunks per XCD (3.2 MB in L2)
  const int ch = xcd * 2 + (sub >> 5);        // 0..15
  const int qt = sub & 31;                    // 0..31
  const int tid = threadIdx.x;
  const int wid = tid >> 6, lane = tid & 63;
  const int quad = lane >> 4, l15 = lane & 15;
  const int wm = wid >> 1, wq = wid & 1;

  const int t0 = ch * TPC;
  const int t1 = (t0 + TPC < TOTAL_MT) ? (t0 + TPC) : TOTAL_MT;
  const int nt = t1 - t0;

  // staging offsets: 4 x 16B units per thread; 1024 units per 64x128 tile (XOR-swizzled)
  u32 goff[4];
  u32 loff0;
  {
    int u0 = wid * 256 + lane;
    loff0 = (u32)(wid * 256) * 8;  // wave-uniform LDS base (HW adds lane*16B)
    #pragma unroll
    for (int it = 0; it < 4; ++it) {
      int u = u0 + it * 64;
      int row = u >> 4, su = u & 15;
      int k8 = su ^ (row & 15);
      goff[it] = (u32)(row * DDIM + k8 * 8);
    }
  }

  // prologue: stage tiles t0, t0+1, t0+2 (nt >= 94 always)
  stage4(mn, B0, t0 + 0, goff, loff0);
  stage4(mn, B1, t0 + 1, goff, loff0);
  stage4(mn, B2, t0 + 2, goff, loff0);

  // B (query) fragments: loop-invariant, in registers (64 VGPRs)
  bf16x8 bq[4][4];  // [ni][s]
  #pragma unroll
  for (int ni = 0; ni < 4; ++ni) {
    int col = qt * QTILE + wq * 64 + ni * 16 + l15;
    #pragma unroll
    for (int s = 0; s < 4; ++s)
      bq[ni][s] = *(const bf16x8*)&qn[(size_t)col * DDIM + (s * 4 + quad) * 8];
  }

  float tv0[4], tv1[4], tv2[4];
  #pragma unroll
  for (int i = 0; i < 4; ++i) { tv0[i] = tv1[i] = tv2[i] = -1e30f; }

  asm volatile("s_waitcnt vmcnt(0)" ::: "memory");  // drain prologue stages (+bq loads)
  asm volatile("s_barrier" ::: "memory");

  // round r: stage min(t0+r+3, t1-1) into B[(r+3)&3]; compute B[r&3];
  // wait vmcnt(8) (retires stage r+1); bare barrier. Always 4 stage-insts/round
  // so the outstanding-count invariant holds in the tail.
  int r = 0;
  #define ROUND(BC, BS)                                                        \
    {                                                                          \
      int ts = t0 + r + 3;                                                     \
      ts = (ts < t1) ? ts : (t1 - 1);                                          \
      stage4(mn, BS, ts, goff, loff0);                                         \
      tileWork(BC, r, wm, quad, l15, bq, tv0, tv1, tv2);                       \
      asm volatile("s_waitcnt vmcnt(8)" ::: "memory");                         \
      asm volatile("s_barrier" ::: "memory");                                  \
      ++r;                                                                     \
      if (r >= nt) break;                                                      \
    }
  while (true) {
    ROUND(B0, B3)
    ROUND(B1, B0)
    ROUND(B2, B1)
    ROUND(B3, B2)
  }
  #undef ROUND

  // cross-quad merge of sorted-3 lists, then coalesced write (3 survivors per wm)
  #pragma unroll
  for (int ni = 0; ni < 4; ++ni) {
    float a0 = tv0[ni], a1 = tv1[ni], a2 = tv2[ni];
    #pragma unroll
    for (int off = 16; off <= 32; off <<= 1) {
      float b0 = __shfl_xor(a0, off, 64);
      float b1 = __shfl_xor(a1, off, 64);
      float b2 = __shfl_xor(a2, off, 64);
      float n0 = fmaxf(a0, b0);
      float n1 = __builtin_amdgcn_fmed3f(a0, b0, fmaxf(a1, b1));
      float n2 = fmaxf(fmaxf(fminf(a1, b0), fminf(a0, b1)), fmaxf(a2, b2));
      a0 = n0; a1 = n1; a2 = n2;
    }
    float v = (quad == 0) ? a0 : ((quad == 1) ? a1 : a2);
    if (quad < 3) {
      int qlocal = wq * 64 + ni * 16 + l15;
      size_t base = (((size_t)qt * NCHUNK + ch) * QTILE + qlocal) * 6 + wm * 3 + quad;
      pval[base] = v;
    }
  }
}

// ---------------- kernel 3: top-8 batches, coalesced fp32 rescore of 64 rows, top-3 ----------------
__global__ __launch_bounds__(256) void kmerge(const float* __restrict__ pval,
                                              const float* __restrict__ q,
                                              const float* __restrict__ mem,
                                              const float* __restrict__ qinv,
                                              const float* __restrict__ minv,
                                              float* __restrict__ out) {
  __shared__ float sv[4][64];
  const int tid = threadIdx.x;
  const int wq = tid >> 6;
  const int lane = tid & 63;
  const int qg = blockIdx.x * 4 + wq;
  const int qt = qg >> 7, ql = qg & 127;

  // load 96 candidates: lanes 0..47 own 2 each
  const int c0 = lane * 2;
  float cv[2] = {-1e31f, -1e31f};
  if (c0 < NCAND) {
    int chn = c0 / 6, rem = c0 - chn * 6;
    size_t b = (((size_t)qt * NCHUNK + chn) * QTILE + ql) * 6 + rem;
    cv[0] = pval[b];
    cv[1] = pval[b + 1];
  }

  // 8 argmax passes (packed val desc, pos asc tiebreak), shuffle-only
  float wv[8]; int wp[8];
  #pragma unroll
  for (int pass = 0; pass < 8; ++pass) {
    float bv = cv[0]; int bp = c0;
    bool g1 = (cv[1] > bv);
    bv = g1 ? cv[1] : bv; bp = g1 ? (c0 + 1) : bp;
    #pragma unroll
    for (int off = 32; off >= 1; off >>= 1) {
      float ov = __shfl_xor(bv, off, 64);
      int op = __shfl_xor(bp, off, 64);
      bool g = (ov > bv) || (ov == bv && op < bp);
      bv = g ? ov : bv; bp = g ? op : bp;
    }
    wv[pass] = bv; wp[pass] = bp;
    if (c0 == bp) cv[0] = -1e31f;
    if (c0 + 1 == bp) cv[1] = -1e31f;
  }

  const float qi = qinv[qg];
  const float* qrow = q + (size_t)qg * DDIM;
  const int e = lane >> 3, f = lane & 7;

  // rescore top-8 batches, 8 rows each; 8 lanes/row, 128B-coalesced segments
  #pragma unroll
  for (int p = 0; p < 8; ++p) {
    int bp = wp[p];
    u32 code = __float_as_uint(wv[p]) & 511u;
    int chn = bp / 6;
    int wm = (bp - chn * 6) / 3;
    int tl = (int)(code >> 2), qd = (int)(code & 3u);
    int row = (chn * TPC + tl) * MTILE + wm * 32 + (e >> 2) * 16 + qd * 4 + (e & 3);
    bool valid = (row < N_M);
    int ra = valid ? row : 0;
    const float* mrow = mem + (size_t)ra * DDIM;
    float s = 0.f;
    #pragma unroll
    for (int i = 0; i < 4; ++i) {
      float4 mv = *(const float4*)&mrow[(f + 8 * i) * 4];
      float4 qv = *(const float4*)&qrow[(f + 8 * i) * 4];
      s += qv.x * mv.x + qv.y * mv.y + qv.z * mv.z + qv.w * mv.w;
    }
    #pragma unroll
    for (int off = 1; off < 8; off <<= 1) s += __shfl_xor(s, off, 64);  // within octet
    s = valid ? (s * qi * minv[ra]) : -1e30f;
    if (f == 0) sv[wq][p * 8 + e] = s;
  }
  __syncthreads();

  // my (row, val): entry = lane -> pass p = lane>>3, elem e2 = lane&7
  float myv = sv[wq][lane];
  {
    int p = lane >> 3, e2 = lane & 7;
    int bp = wp[p];
    u32 code = __float_as_uint(wv[p]) & 511u;
    int chn = bp / 6;
    int wm = (bp - chn * 6) / 3;
    int tl = (int)(code >> 2), qd = (int)(code & 3u);
    int row = (chn * TPC + tl) * MTILE + wm * 32 + (e2 >> 2) * 16 + qd * 4 + (e2 & 3);
    int myrow = (row < N_M) ? row : (N_M + lane);

    // 3 selection passes over 64 exact values (val desc, row asc)
    #pragma unroll
    for (int a = 0; a < 3; ++a) {
      float bv = myv; int bi = myrow;
      #pragma unroll
      for (int off = 32; off >= 1; off >>= 1) {
        float ov = __shfl_xor(bv, off, 64);
        int oi = __shfl_xor(bi, off, 64);
        bool g2 = (ov > bv) || (ov == bv && oi < bi);
        bv = g2 ? ov : bv; bi = g2 ? oi : bi;
      }
      if (lane == 0) {
        out[(size_t)qg * 3 + a] = 1.0f - bv;
        out[(size_t)N_Q * 3 + (size_t)qg * 3 + a] = (float)bi;
      }
      if (myrow == bi) myv = -1e31f;
    }
  }
}

extern "C" void kernel_launch(void* const* d_in, const int* in_sizes, int n_in,
                              void* d_out, int out_size, void* d_ws, size_t ws_size,
                              hipStream_t stream) {
  const float* q = (const float*)d_in[0];
  const float* m = (const float*)d_in[1];

  char* ws = (char*)d_ws;
  size_t off = 0;
  u16* qn = (u16*)(ws + off); off += (size_t)N_Q * DDIM * 2;        // 1 MB
  u16* mn = (u16*)(ws + off); off += (size_t)N_M_PAD * DDIM * 2;    // 25.6 MB
  float* qinv = (float*)(ws + off); off += (size_t)N_Q * 4;
  float* minv = (float*)(ws + off); off += (size_t)N_M_PAD * 4;
  float* pval = (float*)(ws + off); off += (size_t)N_Q * NCAND * 4; // 1.6 MB

  knorm<<<1024, 256, 0, stream>>>(q, m, qn, mn, qinv, minv);
  kgemm<<<NQT * NCHUNK, 256, 0, stream>>>(qn, mn, pval);
  kmerge<<<N_Q / 4, 256, 0, stream>>>(pval, q, m, qinv, minv, (float*)d_out);
}